// Round 4
// baseline (216.412 us; speedup 1.0000x reference)
//
#include <hip/hip_runtime.h>
#include <hip/hip_bf16.h>

#define NUM_TABLES 16
#define ROWS 200000
#define DIM 64
#define LOOKUPS 131072  // == 2^17

typedef float f32x4 __attribute__((ext_vector_type(4)));

// Each lookup row is DIM=64 floats = 16 float4s. One "slot" = one float4.
// Total slots = NUM_TABLES * LOOKUPS * 16 = 33,554,432.
// grid 2048 x block 256 = 524,288 threads -> exactly 64 grid-stride trips.
// NOTE: nontemporal stores were tried (R3) and REGRESSED 187->203us: the
// write stream is half the traffic and nt bypasses the efficient L2 write
// path. Plain stores.
__global__ void grouped_embedding_gather(const int* __restrict__ indices,
                                         const float* __restrict__ weights,
                                         float* __restrict__ out) {
    const long long total_slots = (long long)NUM_TABLES * LOOKUPS * (DIM / 4);
    const long long stride = (long long)gridDim.x * blockDim.x;
    long long s = (long long)blockIdx.x * blockDim.x + threadIdx.x;
#pragma unroll 8
    for (; s < total_slots; s += stride) {
        const long long lookup = s >> 4;          // which (table, pos)
        const int slot = (int)(s & 15);           // float4 index within row
        const int table = (int)(lookup >> 17);    // LOOKUPS == 2^17
        const int idx = indices[lookup];          // gather index into table
        const f32x4* __restrict__ src = reinterpret_cast<const f32x4*>(
            weights + (size_t)table * ((size_t)ROWS * DIM) + (size_t)idx * DIM);
        f32x4* __restrict__ dst =
            reinterpret_cast<f32x4*>(out + (size_t)lookup * DIM) + slot;
        *dst = src[slot];
    }
}

extern "C" void kernel_launch(void* const* d_in, const int* in_sizes, int n_in,
                              void* d_out, int out_size, void* d_ws, size_t ws_size,
                              hipStream_t stream) {
    const int* indices = (const int*)d_in[0];
    const float* weights = (const float*)d_in[1];
    float* out = (float*)d_out;

    const int block = 256;
    const long long total_slots = (long long)NUM_TABLES * LOOKUPS * (DIM / 4);
    long long blocks_needed = (total_slots + block - 1) / block;
    int grid = (int)((blocks_needed < 2048) ? blocks_needed : 2048);

    grouped_embedding_gather<<<grid, block, 0, stream>>>(indices, weights, out);
}

// Round 5
// 186.768 us; speedup vs baseline: 1.1587x; 1.1587x over previous
//
#include <hip/hip_runtime.h>
#include <hip/hip_bf16.h>

#define NUM_TABLES 16
#define ROWS 200000
#define DIM 64
#define LOOKUPS 131072  // == 2^17

// Each lookup row is DIM=64 floats = 16 float4s. One "slot" = one float4.
// Total slots = NUM_TABLES * LOOKUPS * 16 = 33,554,432.
// grid 2048 x block 256 = 524,288 threads -> exactly 64 grid-stride trips.
//
// Experiment log:
//   R1: this structure (integer div, no pragma)        -> 187 us  (best)
//   R3: + nontemporal store + unroll 4                 -> 203 us  (nt hurts writes)
//   R4: plain store + unroll 8                         -> 216 us  (unroll hurts schedule)
// Conclusion: let the compiler schedule the simple loop; max-occupancy
// grid-stride already covers one table per 4 trips (51.2 MB, L3-resident).
__global__ void grouped_embedding_gather(const int* __restrict__ indices,
                                         const float* __restrict__ weights,
                                         float* __restrict__ out) {
    const long long total_slots = (long long)NUM_TABLES * LOOKUPS * (DIM / 4);
    const long long stride = (long long)gridDim.x * blockDim.x;
    for (long long s = (long long)blockIdx.x * blockDim.x + threadIdx.x;
         s < total_slots; s += stride) {
        const long long lookup = s >> 4;          // which (table, pos)
        const int slot = (int)(s & 15);           // float4 index within row
        const int table = (int)(lookup >> 17);    // LOOKUPS == 2^17
        const int idx = indices[lookup];          // gather index into table
        const float4* __restrict__ src = reinterpret_cast<const float4*>(
            weights + (size_t)table * ((size_t)ROWS * DIM) + (size_t)idx * DIM);
        float4* __restrict__ dst = reinterpret_cast<float4*>(
            out + (size_t)lookup * DIM);
        dst[slot] = src[slot];
    }
}

extern "C" void kernel_launch(void* const* d_in, const int* in_sizes, int n_in,
                              void* d_out, int out_size, void* d_ws, size_t ws_size,
                              hipStream_t stream) {
    const int* indices = (const int*)d_in[0];
    const float* weights = (const float*)d_in[1];
    float* out = (float*)d_out;

    const int block = 256;
    const long long total_slots = (long long)NUM_TABLES * LOOKUPS * (DIM / 4);
    long long blocks_needed = (total_slots + block - 1) / block;
    int grid = (int)((blocks_needed < 2048) ? blocks_needed : 2048);

    grouped_embedding_gather<<<grid, block, 0, stream>>>(indices, weights, out);
}